// Round 3
// baseline (814.908 us; speedup 1.0000x reference)
//
#include <hip/hip_runtime.h>
#include <cstddef>
#include <cstdint>

// B=2, C=8, L=512, CH=256, CW=8, NH=8, D=256, ROT=32. 128 heads total.
// head = (b*8+c)*8+n ; q/k/v bf16 [head][l][256] ; vt bf16 [head][d][512]
// conv / a2 feature layout is W-MAJOR: [bl*8+c][w*256 + h]  (h = ch index)

typedef unsigned short u16;
typedef unsigned int u32;
typedef __attribute__((ext_vector_type(8))) short short8;
typedef __attribute__((ext_vector_type(4))) float floatx4;

__device__ __forceinline__ float bf2f(u16 u) {
  union { u32 i; float f; } v; v.i = ((u32)u) << 16; return v.f;
}
__device__ __forceinline__ u16 f2bf(float f) {
  union { float f; u32 i; } v; v.f = f;
  return (u16)((v.i + 0x7fffu + ((v.i >> 16) & 1u)) >> 16);
}

// ---------------- weight convert fp32 -> bf16, layout [c][g][h] kept --------
__global__ __launch_bounds__(256) void convert_w_kernel(
    const float* __restrict__ wq, const float* __restrict__ wk,
    const float* __restrict__ wv, const float* __restrict__ wo,
    u16* __restrict__ wbf) {
  int mat = blockIdx.y;
  const float* src = (mat == 0) ? wq : (mat == 1) ? wk : (mat == 2) ? wv : wo;
  int idx = blockIdx.x * 256 + threadIdx.x;  // 524288 elems per matrix
  wbf[(size_t)mat * 524288 + idx] = f2bf(src[idx]);
}

// ------------- fused conv: q,k,v convs in one pass, bf16 w-major out --------
// block = (bl, ihalf); thread: i = ih*128 + (t&127), sh = t>>7 covers 12 (s,co)
__global__ __launch_bounds__(256) void conv_fused_kernel(
    const float* __restrict__ x,
    const float* __restrict__ wq, const float* __restrict__ wk,
    const float* __restrict__ wv,
    u16* __restrict__ oq, u16* __restrict__ ok, u16* __restrict__ ov) {
  __shared__ float wl[1728];
  int t = threadIdx.x;
  for (int i2 = t; i2 < 1728; i2 += 256)
    wl[i2] = (i2 < 576) ? wq[i2] : (i2 < 1152 ? wk[i2 - 576] : wv[i2 - 1152]);
  __syncthreads();

  int bl = blockIdx.x >> 1, ih = blockIdx.x & 1;
  int b = bl >> 9, l = bl & 511;
  int il = t & 127, sh = t >> 7;
  int i = ih * 128 + il;

  float acc[12][8];
#pragma unroll
  for (int p = 0; p < 12; ++p)
#pragma unroll
    for (int j = 0; j < 8; ++j) acc[p][j] = 0.f;

  for (int ci = 0; ci < 8; ++ci) {
    const float* xc = x + (((size_t)(b * 8 + ci) * 512 + l) << 11);
    float xr[3][10];
#pragma unroll
    for (int di = 0; di < 3; ++di) {
      int gi = i + di - 1;
      xr[di][0] = 0.f; xr[di][9] = 0.f;
      if (gi >= 0 && gi < 256) {
        float4 a = *(const float4*)(xc + gi * 8);
        float4 bq = *(const float4*)(xc + gi * 8 + 4);
        xr[di][1] = a.x; xr[di][2] = a.y; xr[di][3] = a.z; xr[di][4] = a.w;
        xr[di][5] = bq.x; xr[di][6] = bq.y; xr[di][7] = bq.z; xr[di][8] = bq.w;
      } else {
#pragma unroll
        for (int j = 1; j < 9; ++j) xr[di][j] = 0.f;
      }
    }
#pragma unroll
    for (int p = 0; p < 12; ++p) {
      int pp = sh * 12 + p;
      int s = pp >> 3, co = pp & 7;
      const float* wp = &wl[s * 576 + (co * 8 + ci) * 9];
      float w00 = wp[0], w01 = wp[1], w02 = wp[2];
      float w10 = wp[3], w11 = wp[4], w12 = wp[5];
      float w20 = wp[6], w21 = wp[7], w22 = wp[8];
#pragma unroll
      for (int j = 0; j < 8; ++j) {
        acc[p][j] += w00 * xr[0][j] + w01 * xr[0][j + 1] + w02 * xr[0][j + 2]
                   + w10 * xr[1][j] + w11 * xr[1][j + 1] + w12 * xr[1][j + 2]
                   + w20 * xr[2][j] + w21 * xr[2][j + 1] + w22 * xr[2][j + 2];
      }
    }
  }
  // w-major store: ob[(bl*8+co)*2048 + j*256 + i] ; lanes have consecutive i
#pragma unroll
  for (int p = 0; p < 12; ++p) {
    int pp = sh * 12 + p;
    int s = pp >> 3, co = pp & 7;
    u16* ob = (s == 0) ? oq : (s == 1) ? ok : ov;
    size_t base = ((size_t)(bl * 8 + co)) << 11;
#pragma unroll
    for (int j = 0; j < 8; ++j) ob[base + j * 256 + i] = f2bf(acc[p][j]);
  }
}

// ---------------- MFMA mlin: D[g][col] = sum_h W[c][g][h] * Z[c][h][col] ----
// col = bl*8+w (8192 per c). Block tile 128g x 128col, 4 waves (2x2 of 64x64).
// K=256 in 4 chunks of 64. LDS rows are 128B with 16B-slot XOR swizzle (T2).
// MODE 0: q/k head layout + rope. MODE 1: v head layout. MODE 2: fp32 out.
template <int MODE>
__global__ __launch_bounds__(256) void mlin_mfma_kernel(
    const u16* __restrict__ zin,   // [(bl*8+c)][w*256+h] bf16
    const u16* __restrict__ wbf,   // [c][g][h] bf16
    void* __restrict__ outp) {
  __shared__ u16 lds_a[8192];      // 128 g-rows x 64 k (128B rows, swizzled)
  __shared__ u16 lds_b[8192];      // 128 col-rows x 64 k

  int tid = threadIdx.x;
  int wv = tid >> 6, lane = tid & 63;
  int fn = lane & 15, fq = lane >> 4;
  int wr = wv & 1, wc = wv >> 1;

  int bx = blockIdx.x;             // 8 c x 64 cblk x 2 gblk = 1024
  int c = bx >> 7;
  int cblk = (bx >> 1) & 63;
  int gblk = bx & 1;
  int g0 = gblk * 128;
  int col0 = cblk * 128;

  const u16* wsrc = wbf + ((size_t)c << 16);

  floatx4 acc[4][4];
#pragma unroll
  for (int mf = 0; mf < 4; ++mf)
#pragma unroll
    for (int nf = 0; nf < 4; ++nf) acc[mf][nf] = (floatx4){0.f, 0.f, 0.f, 0.f};

  for (int kt = 0; kt < 4; ++kt) {
    int h0 = kt * 64;
#pragma unroll
    for (int it = 0; it < 4; ++it) {
      int li = it * 256 + tid;
      int rr = li >> 3, hs = li & 7;      // rr: g-row / col-row, hs: 16B slot
      uint4 ua = *(const uint4*)(wsrc + (size_t)(g0 + rr) * 256 + h0 + hs * 8);
      *(uint4*)((char*)lds_a + rr * 128 + ((hs ^ (rr & 7)) << 4)) = ua;
      uint4 ub = *(const uint4*)(zin +
          ((size_t)((cblk * 16 + (rr >> 3)) * 8 + c) << 11) + (rr & 7) * 256 +
          h0 + hs * 8);
      *(uint4*)((char*)lds_b + rr * 128 + ((hs ^ (rr & 7)) << 4)) = ub;
    }
    __syncthreads();
#pragma unroll
    for (int kc = 0; kc < 2; ++kc) {
      short8 af[4], bf[4];
#pragma unroll
      for (int mf = 0; mf < 4; ++mf) {
        int row = wr * 64 + mf * 16 + fn;
        af[mf] = *(const short8*)((const char*)lds_a + row * 128 +
                                  (((kc * 4 + fq) ^ (row & 7)) << 4));
      }
#pragma unroll
      for (int nf = 0; nf < 4; ++nf) {
        int row = wc * 64 + nf * 16 + fn;
        bf[nf] = *(const short8*)((const char*)lds_b + row * 128 +
                                  (((kc * 4 + fq) ^ (row & 7)) << 4));
      }
#pragma unroll
      for (int mf = 0; mf < 4; ++mf)
#pragma unroll
        for (int nf = 0; nf < 4; ++nf)
          acc[mf][nf] = __builtin_amdgcn_mfma_f32_16x16x32_bf16(
              af[mf], bf[nf], acc[mf][nf], 0, 0, 0);
    }
    __syncthreads();
  }

  // epilogue: D row = g = g0+wr*64+mf*16+fq*4+r ; D col = col0+wc*64+nf*16+fn
  if (MODE == 2) {
    float* op = (float*)outp;
#pragma unroll
    for (int nf = 0; nf < 4; ++nf) {
      int col = col0 + wc * 64 + nf * 16 + fn;
      int bl = col >> 3, w = col & 7;
      int b = bl >> 9, l = bl & 511;
      size_t rowoff = ((size_t)((b * 8 + c) * 512 + l) << 11) + w;
#pragma unroll
      for (int mf = 0; mf < 4; ++mf)
#pragma unroll
        for (int r = 0; r < 4; ++r) {
          int g = g0 + wr * 64 + mf * 16 + fq * 4 + r;
          op[rowoff + g * 8] = acc[mf][nf][r];
        }
    }
  } else {
    u16* op = (u16*)outp;
#pragma unroll
    for (int nf = 0; nf < 4; ++nf) {
      int col = col0 + wc * 64 + nf * 16 + fn;
      int bl = col >> 3, w = col & 7;
      int b = bl >> 9, l = bl & 511;
      size_t base = ((size_t)((b * 8 + c) * 8) << 17) + ((size_t)l << 8);
#pragma unroll
      for (int mf = 0; mf < 4; ++mf)
#pragma unroll
        for (int r = 0; r < 4; ++r) {
          int g = g0 + wr * 64 + mf * 16 + fq * 4 + r;
          float val = acc[mf][nf][r];
          if (MODE == 0) {
            float other = __shfl_xor(val, 1);  // partner d^1 lives in lane fn^1
            int d = ((g & 31) << 3) + w;
            if (d < 32) {
              int p = d >> 1;
              float ang = (float)l * __expf(-(float)p * 0.57564627324851142f);
              float cv = cosf(ang), sv = sinf(ang);
              val = (d & 1) ? (val * cv + other * sv) : (val * cv - other * sv);
            }
          }
          int n = g >> 5, d2 = ((g & 31) << 3) + w;
          op[base + ((size_t)n << 17) + d2] = f2bf(val);
        }
    }
  }
}

// ---------------- V transpose: vt[head][d][m] = vb[head][m][d] --------------
__global__ __launch_bounds__(256) void transpose_v_kernel(const u16* __restrict__ vb,
                                                          u16* __restrict__ vt) {
  __shared__ u16 tile[64 * 66];
  int bx = blockIdx.x;                  // head*32 + mt*4 + dt
  int head = bx >> 5, mt = (bx >> 2) & 7, dt = bx & 3;
  size_t off = (size_t)head << 17;
  int t = threadIdx.x;
#pragma unroll
  for (int it = 0; it < 2; ++it) {
    int li = it * 256 + t;
    int r = li >> 3, cs = li & 7;
    uint4 u = *(const uint4*)(vb + off + (size_t)(mt * 64 + r) * 256 + dt * 64 + cs * 8);
    *(u32*)&tile[r * 66 + cs * 8 + 0] = u.x;
    *(u32*)&tile[r * 66 + cs * 8 + 2] = u.y;
    *(u32*)&tile[r * 66 + cs * 8 + 4] = u.z;
    *(u32*)&tile[r * 66 + cs * 8 + 6] = u.w;
  }
  __syncthreads();
#pragma unroll
  for (int it = 0; it < 2; ++it) {
    int li = it * 256 + t;
    int r = li >> 3, cs = li & 7;   // r = d-local, cs = m-seg
    u16 tmp[8];
#pragma unroll
    for (int jj = 0; jj < 8; ++jj) tmp[jj] = tile[(cs * 8 + jj) * 66 + r];
    uint4 o;
    o.x = (u32)tmp[0] | ((u32)tmp[1] << 16);
    o.y = (u32)tmp[2] | ((u32)tmp[3] << 16);
    o.z = (u32)tmp[4] | ((u32)tmp[5] << 16);
    o.w = (u32)tmp[6] | ((u32)tmp[7] << 16);
    *(uint4*)(vt + off + (size_t)(dt * 64 + r) * 512 + mt * 64 + cs * 8) = o;
  }
}

// ---------------- MFMA attention: 32 q-rows per block -----------------------
// v3: direct global->reg fragments (no K/V LDS staging) + explicit register
// software-pipeline: ping-pong K/V fragment buffers (1 chunk ahead), 8-deep
// rotating prefetch for prev (HBM latency), conflict-free softmax, XCD swizzle.
__global__ __launch_bounds__(256) void attn_kernel(
    const u16* __restrict__ q, const u16* __restrict__ k,
    const u16* __restrict__ vt, const float* __restrict__ prev,
    float* __restrict__ qk_out, u16* __restrict__ a2) {
  __shared__ u16 s_bf[32 * 520];      // S / P, bf16, stride 520 u16
  __shared__ float rinv[32];

  int bx = blockIdx.x;
  int bid = (bx & 7) * 256 + (bx >> 3);   // XCD swizzle: 16 blocks/head -> 1 XCD
  int head = bid >> 4;
  int l0 = (bid & 15) << 5;
  int b = head >> 6, c = (head >> 3) & 7, nh = head & 7;
  size_t qoff = (size_t)head << 17;
  size_t poff = (size_t)head << 18;
  int tid = threadIdx.x;
  int w = tid >> 6, lane = tid & 63;
  int fn = lane & 15, fq = lane >> 4;
  int rt = w & 1, ct = w >> 1;

  // preload Q fragments (16 rows for this wave, full K=256)
  short8 qf[8];
  const u16* qrow = q + qoff + (size_t)(l0 + rt * 16 + fn) * 256 + fq * 8;
#pragma unroll
  for (int kc = 0; kc < 8; ++kc) qf[kc] = *(const short8*)(qrow + kc * 32);

  const u16* kbase = k + qoff + (size_t)(ct * 16 + fn) * 256 + fq * 8;
  const float* prow = prev + poff + (size_t)(l0 + rt * 16 + fq * 4) * 512 + ct * 16 + fn;
  float* qrow_out = qk_out + poff + (size_t)(l0 + rt * 16 + fq * 4) * 512 + ct * 16 + fn;

  // ---- S = QK^T/16 + prev : register-pipelined over 16 chunks of 32 m ----
  short8 kfa[8], kfb[8];
  float pvb[8][4];

#define LOADK(BUF, MC) do {                                                   \
    const u16* _kr = kbase + ((size_t)((MC) * 32) << 8);                      \
    _Pragma("unroll") for (int _kc = 0; _kc < 8; ++_kc)                       \
      BUF[_kc] = *(const short8*)(_kr + _kc * 32);                            \
  } while (0)

#define LOADP(MC) do { if ((MC) < 16) {                                       \
    _Pragma("unroll") for (int _r = 0; _r < 4; ++_r)                          \
      pvb[(MC) & 7][_r] = prow[(size_t)_r * 512 + (MC) * 32];                 \
  } } while (0)

#define QKSTEP(BUF, MC) do {                                                  \
    floatx4 _acc = {0.f, 0.f, 0.f, 0.f};                                      \
    _Pragma("unroll") for (int _kc = 0; _kc < 8; ++_kc)                       \
      _acc = __builtin_amdgcn_mfma_f32_16x16x32_bf16(qf[_kc], BUF[_kc], _acc, \
                                                     0, 0, 0);                \
    _Pragma("unroll") for (int _r = 0; _r < 4; ++_r) {                        \
      float _sv = _acc[_r] * 0.0625f + pvb[(MC) & 7][_r];                     \
      qrow_out[(size_t)_r * 512 + (MC) * 32] = _sv;                           \
      s_bf[(rt * 16 + fq * 4 + _r) * 520 + (MC) * 32 + ct * 16 + fn] =        \
          f2bf(_sv);                                                          \
    }                                                                         \
    LOADP((MC) + 8);                                                          \
  } while (0)

  LOADP(0); LOADP(1); LOADP(2); LOADP(3);
  LOADP(4); LOADP(5); LOADP(6); LOADP(7);
  LOADK(kfa, 0);
#pragma unroll
  for (int m2 = 0; m2 < 8; ++m2) {
    LOADK(kfb, 2 * m2 + 1);
    QKSTEP(kfa, 2 * m2);
    if (m2 < 7) LOADK(kfa, 2 * m2 + 2);
    QKSTEP(kfb, 2 * m2 + 1);
  }
  __syncthreads();

  // ---- softmax over rows (8 threads/row; slot = ii*8+sseg => conflict-free) -
  {
    int srow = tid >> 3, sseg = tid & 7;
    u16* sp = &s_bf[srow * 520 + sseg * 8];
    float mx = -1e30f;
#pragma unroll
    for (int ii = 0; ii < 8; ++ii) {
      uint4 u = *(const uint4*)(sp + ii * 64);
      mx = fmaxf(mx, fmaxf(fmaxf(fmaxf(bf2f(u.x & 0xffff), bf2f(u.x >> 16)),
                                 fmaxf(bf2f(u.y & 0xffff), bf2f(u.y >> 16))),
                           fmaxf(fmaxf(bf2f(u.z & 0xffff), bf2f(u.z >> 16)),
                                 fmaxf(bf2f(u.w & 0xffff), bf2f(u.w >> 16)))));
    }
#pragma unroll
    for (int o = 1; o < 8; o <<= 1) mx = fmaxf(mx, __shfl_xor(mx, o));
    float sum = 0.f;
#pragma unroll
    for (int ii = 0; ii < 8; ++ii) {
      uint4 u = *(const uint4*)(sp + ii * 64);
      float e0 = __expf(bf2f(u.x & 0xffff) - mx), e1 = __expf(bf2f(u.x >> 16) - mx);
      float e2 = __expf(bf2f(u.y & 0xffff) - mx), e3 = __expf(bf2f(u.y >> 16) - mx);
      float e4 = __expf(bf2f(u.z & 0xffff) - mx), e5 = __expf(bf2f(u.z >> 16) - mx);
      float e6 = __expf(bf2f(u.w & 0xffff) - mx), e7 = __expf(bf2f(u.w >> 16) - mx);
      sum += e0 + e1 + e2 + e3 + e4 + e5 + e6 + e7;
      uint4 o;
      o.x = (u32)f2bf(e0) | ((u32)f2bf(e1) << 16);
      o.y = (u32)f2bf(e2) | ((u32)f2bf(e3) << 16);
      o.z = (u32)f2bf(e4) | ((u32)f2bf(e5) << 16);
      o.w = (u32)f2bf(e6) | ((u32)f2bf(e7) << 16);
      *(uint4*)(sp + ii * 64) = o;
    }
#pragma unroll
    for (int o = 1; o < 8; o <<= 1) sum += __shfl_xor(sum, o);
    if (sseg == 0) rinv[srow] = 1.0f / sum;
  }
  __syncthreads();

  // ---- O = P V : register-pipelined over 16 chunks of 32 m ----
  floatx4 oacc[8];
#pragma unroll
  for (int dt = 0; dt < 8; ++dt) oacc[dt] = (floatx4){0.f, 0.f, 0.f, 0.f};

  const u16* vbase = vt + qoff + (size_t)(ct * 128 + fn) * 512 + fq * 8;
  const u16* arow = &s_bf[(rt * 16 + fn) * 520 + fq * 8];

  short8 vfa[8], vfb[8], afa, afb;

#define LOADV(BUF, AF, MC) do {                                               \
    const u16* _vr = vbase + (size_t)((MC) * 32);                             \
    _Pragma("unroll") for (int _dt = 0; _dt < 8; ++_dt)                       \
      BUF[_dt] = *(const short8*)(_vr + (size_t)_dt * 16 * 512);              \
    AF = *(const short8*)(arow + (MC) * 32);                                  \
  } while (0)

#define PVSTEP(BUF, AF) do {                                                  \
    _Pragma("unroll") for (int _dt = 0; _dt < 8; ++_dt)                       \
      oacc[_dt] = __builtin_amdgcn_mfma_f32_16x16x32_bf16(AF, BUF[_dt],       \
                                                          oacc[_dt], 0, 0, 0);\
  } while (0)

  LOADV(vfa, afa, 0);
#pragma unroll
  for (int m2 = 0; m2 < 8; ++m2) {
    LOADV(vfb, afb, 2 * m2 + 1);
    PVSTEP(vfa, afa);
    if (m2 < 7) LOADV(vfa, afa, 2 * m2 + 2);
    PVSTEP(vfb, afb);
  }

  float riv[4];
#pragma unroll
  for (int r = 0; r < 4; ++r) riv[r] = rinv[rt * 16 + fq * 4 + r];
#pragma unroll
  for (int dt = 0; dt < 8; ++dt) {
#pragma unroll
    for (int r = 0; r < 4; ++r) {
      int lrow = l0 + rt * 16 + fq * 4 + r;
      int d = ct * 128 + dt * 16 + fn;
      int bl = b * 512 + lrow;
      // w-major a2: feature f = nh*256+d -> [ (f&7)*256 + (f>>3) ]
      a2[(size_t)(bl * 8 + c) * 2048 + ((d & 7) << 8) + (nh << 5) + (d >> 3)] =
          f2bf(oacc[dt][r] * riv[r]);
    }
  }
#undef LOADK
#undef LOADP
#undef QKSTEP
#undef LOADV
#undef PVSTEP
}

extern "C" void kernel_launch(void* const* d_in, const int* in_sizes, int n_in,
                              void* d_out, int out_size, void* d_ws, size_t ws_size,
                              hipStream_t stream) {
  const float* x    = (const float*)d_in[0];
  const float* prev = (const float*)d_in[1];
  const float* cqw  = (const float*)d_in[2];
  const float* ckw  = (const float*)d_in[3];
  const float* cvw  = (const float*)d_in[4];
  const float* wq   = (const float*)d_in[5];
  const float* wk   = (const float*)d_in[6];
  const float* wv   = (const float*)d_in[7];
  const float* wo   = (const float*)d_in[8];

  float* out    = (float*)d_out;
  float* qk_out = out + 16777216;

  char* wsb = (char*)d_ws;
  u16* wbf    = (u16*)wsb;                         // 4 MB (in old 8 MB slot)
  u16* convq  = (u16*)(wsb + 8388608);             // each 33.5 MB
  u16* convk  = convq + 16777216;
  u16* convv  = convk + 16777216;
  u16* qb     = convv + 16777216;
  u16* kb     = qb + 16777216;
  u16* vb     = kb + 16777216;
  u16* vtb    = vb + 16777216;
  u16* a2     = vtb + 16777216;
  // total ~277 MB

  convert_w_kernel<<<dim3(2048, 4), 256, 0, stream>>>(wq, wk, wv, wo, wbf);
  conv_fused_kernel<<<2048, 256, 0, stream>>>(x, cqw, ckw, cvw, convq, convk, convv);
  mlin_mfma_kernel<0><<<1024, 256, 0, stream>>>(convq, wbf, qb);
  mlin_mfma_kernel<0><<<1024, 256, 0, stream>>>(convk, wbf + 524288, kb);
  mlin_mfma_kernel<1><<<1024, 256, 0, stream>>>(convv, wbf + 1048576, vb);
  transpose_v_kernel<<<4096, 256, 0, stream>>>(vb, vtb);
  attn_kernel<<<2048, 256, 0, stream>>>(qb, kb, vtb, prev, qk_out, a2);
  mlin_mfma_kernel<2><<<1024, 256, 0, stream>>>(a2, wbf + 1572864, out);
}

// Round 4
// 716.399 us; speedup vs baseline: 1.1375x; 1.1375x over previous
//
#include <hip/hip_runtime.h>
#include <cstddef>
#include <cstdint>

// B=2, C=8, L=512, CH=256, CW=8, NH=8, D=256, ROT=32. 128 heads total.
// head = (b*8+c)*8+n ; q/k/v bf16 [head][l][256]
// vt2 bf16 chunk-tiled: [head][mc(16)][d(256)][mloc(32)]
// conv / a2 feature layout is W-MAJOR: [bl*8+c][w*256 + h]  (h = ch index)

typedef unsigned short u16;
typedef unsigned int u32;
typedef __attribute__((ext_vector_type(8))) short short8;
typedef __attribute__((ext_vector_type(4))) float floatx4;

__device__ __forceinline__ float bf2f(u16 u) {
  union { u32 i; float f; } v; v.i = ((u32)u) << 16; return v.f;
}
__device__ __forceinline__ u16 f2bf(float f) {
  union { float f; u32 i; } v; v.f = f;
  return (u16)((v.i + 0x7fffu + ((v.i >> 16) & 1u)) >> 16);
}
__device__ __forceinline__ void gl_lds16(const void* g, void* l) {
  __builtin_amdgcn_global_load_lds(
      (__attribute__((address_space(1))) void*)(g),
      (__attribute__((address_space(3))) void*)(l), 16, 0, 0);
}

// ---------------- weight convert fp32 -> bf16, layout [c][g][h] kept --------
__global__ __launch_bounds__(256) void convert_w_kernel(
    const float* __restrict__ wq, const float* __restrict__ wk,
    const float* __restrict__ wv, const float* __restrict__ wo,
    u16* __restrict__ wbf) {
  int mat = blockIdx.y;
  const float* src = (mat == 0) ? wq : (mat == 1) ? wk : (mat == 2) ? wv : wo;
  int idx = blockIdx.x * 256 + threadIdx.x;  // 524288 elems per matrix
  wbf[(size_t)mat * 524288 + idx] = f2bf(src[idx]);
}

// ------------- fused conv: q,k,v convs in one pass, bf16 w-major out --------
__global__ __launch_bounds__(256) void conv_fused_kernel(
    const float* __restrict__ x,
    const float* __restrict__ wq, const float* __restrict__ wk,
    const float* __restrict__ wv,
    u16* __restrict__ oq, u16* __restrict__ ok, u16* __restrict__ ov) {
  __shared__ float wl[1728];
  int t = threadIdx.x;
  for (int i2 = t; i2 < 1728; i2 += 256)
    wl[i2] = (i2 < 576) ? wq[i2] : (i2 < 1152 ? wk[i2 - 576] : wv[i2 - 1152]);
  __syncthreads();

  int bl = blockIdx.x >> 1, ih = blockIdx.x & 1;
  int b = bl >> 9, l = bl & 511;
  int il = t & 127, sh = t >> 7;
  int i = ih * 128 + il;

  float acc[12][8];
#pragma unroll
  for (int p = 0; p < 12; ++p)
#pragma unroll
    for (int j = 0; j < 8; ++j) acc[p][j] = 0.f;

  for (int ci = 0; ci < 8; ++ci) {
    const float* xc = x + (((size_t)(b * 8 + ci) * 512 + l) << 11);
    float xr[3][10];
#pragma unroll
    for (int di = 0; di < 3; ++di) {
      int gi = i + di - 1;
      xr[di][0] = 0.f; xr[di][9] = 0.f;
      if (gi >= 0 && gi < 256) {
        float4 a = *(const float4*)(xc + gi * 8);
        float4 bq = *(const float4*)(xc + gi * 8 + 4);
        xr[di][1] = a.x; xr[di][2] = a.y; xr[di][3] = a.z; xr[di][4] = a.w;
        xr[di][5] = bq.x; xr[di][6] = bq.y; xr[di][7] = bq.z; xr[di][8] = bq.w;
      } else {
#pragma unroll
        for (int j = 1; j < 9; ++j) xr[di][j] = 0.f;
      }
    }
#pragma unroll
    for (int p = 0; p < 12; ++p) {
      int pp = sh * 12 + p;
      int s = pp >> 3, co = pp & 7;
      const float* wp = &wl[s * 576 + (co * 8 + ci) * 9];
      float w00 = wp[0], w01 = wp[1], w02 = wp[2];
      float w10 = wp[3], w11 = wp[4], w12 = wp[5];
      float w20 = wp[6], w21 = wp[7], w22 = wp[8];
#pragma unroll
      for (int j = 0; j < 8; ++j) {
        acc[p][j] += w00 * xr[0][j] + w01 * xr[0][j + 1] + w02 * xr[0][j + 2]
                   + w10 * xr[1][j] + w11 * xr[1][j + 1] + w12 * xr[1][j + 2]
                   + w20 * xr[2][j] + w21 * xr[2][j + 1] + w22 * xr[2][j + 2];
      }
    }
  }
#pragma unroll
  for (int p = 0; p < 12; ++p) {
    int pp = sh * 12 + p;
    int s = pp >> 3, co = pp & 7;
    u16* ob = (s == 0) ? oq : (s == 1) ? ok : ov;
    size_t base = ((size_t)(bl * 8 + co)) << 11;
#pragma unroll
    for (int j = 0; j < 8; ++j) ob[base + j * 256 + i] = f2bf(acc[p][j]);
  }
}

// ---------------- MFMA mlin: D[g][col] = sum_h W[c][g][h] * Z[c][h][col] ----
template <int MODE>
__global__ __launch_bounds__(256) void mlin_mfma_kernel(
    const u16* __restrict__ zin,   // [(bl*8+c)][w*256+h] bf16
    const u16* __restrict__ wbf,   // [c][g][h] bf16
    void* __restrict__ outp) {
  __shared__ u16 lds_a[8192];      // 128 g-rows x 64 k (128B rows, swizzled)
  __shared__ u16 lds_b[8192];      // 128 col-rows x 64 k

  int tid = threadIdx.x;
  int wv = tid >> 6, lane = tid & 63;
  int fn = lane & 15, fq = lane >> 4;
  int wr = wv & 1, wc = wv >> 1;

  int bx = blockIdx.x;             // 8 c x 64 cblk x 2 gblk = 1024
  int c = bx >> 7;
  int cblk = (bx >> 1) & 63;
  int gblk = bx & 1;
  int g0 = gblk * 128;
  int col0 = cblk * 128;

  const u16* wsrc = wbf + ((size_t)c << 16);

  floatx4 acc[4][4];
#pragma unroll
  for (int mf = 0; mf < 4; ++mf)
#pragma unroll
    for (int nf = 0; nf < 4; ++nf) acc[mf][nf] = (floatx4){0.f, 0.f, 0.f, 0.f};

  for (int kt = 0; kt < 4; ++kt) {
    int h0 = kt * 64;
#pragma unroll
    for (int it = 0; it < 4; ++it) {
      int li = it * 256 + tid;
      int rr = li >> 3, hs = li & 7;      // rr: g-row / col-row, hs: 16B slot
      uint4 ua = *(const uint4*)(wsrc + (size_t)(g0 + rr) * 256 + h0 + hs * 8);
      *(uint4*)((char*)lds_a + rr * 128 + ((hs ^ (rr & 7)) << 4)) = ua;
      uint4 ub = *(const uint4*)(zin +
          ((size_t)((cblk * 16 + (rr >> 3)) * 8 + c) << 11) + (rr & 7) * 256 +
          h0 + hs * 8);
      *(uint4*)((char*)lds_b + rr * 128 + ((hs ^ (rr & 7)) << 4)) = ub;
    }
    __syncthreads();
#pragma unroll
    for (int kc = 0; kc < 2; ++kc) {
      short8 af[4], bf[4];
#pragma unroll
      for (int mf = 0; mf < 4; ++mf) {
        int row = wr * 64 + mf * 16 + fn;
        af[mf] = *(const short8*)((const char*)lds_a + row * 128 +
                                  (((kc * 4 + fq) ^ (row & 7)) << 4));
      }
#pragma unroll
      for (int nf = 0; nf < 4; ++nf) {
        int row = wc * 64 + nf * 16 + fn;
        bf[nf] = *(const short8*)((const char*)lds_b + row * 128 +
                                  (((kc * 4 + fq) ^ (row & 7)) << 4));
      }
#pragma unroll
      for (int mf = 0; mf < 4; ++mf)
#pragma unroll
        for (int nf = 0; nf < 4; ++nf)
          acc[mf][nf] = __builtin_amdgcn_mfma_f32_16x16x32_bf16(
              af[mf], bf[nf], acc[mf][nf], 0, 0, 0);
    }
    __syncthreads();
  }

  if (MODE == 2) {
    float* op = (float*)outp;
#pragma unroll
    for (int nf = 0; nf < 4; ++nf) {
      int col = col0 + wc * 64 + nf * 16 + fn;
      int bl = col >> 3, w = col & 7;
      int b = bl >> 9, l = bl & 511;
      size_t rowoff = ((size_t)((b * 8 + c) * 512 + l) << 11) + w;
#pragma unroll
      for (int mf = 0; mf < 4; ++mf)
#pragma unroll
        for (int r = 0; r < 4; ++r) {
          int g = g0 + wr * 64 + mf * 16 + fq * 4 + r;
          op[rowoff + g * 8] = acc[mf][nf][r];
        }
    }
  } else {
    u16* op = (u16*)outp;
#pragma unroll
    for (int nf = 0; nf < 4; ++nf) {
      int col = col0 + wc * 64 + nf * 16 + fn;
      int bl = col >> 3, w = col & 7;
      int b = bl >> 9, l = bl & 511;
      size_t base = ((size_t)((b * 8 + c) * 8) << 17) + ((size_t)l << 8);
#pragma unroll
      for (int mf = 0; mf < 4; ++mf)
#pragma unroll
        for (int r = 0; r < 4; ++r) {
          int g = g0 + wr * 64 + mf * 16 + fq * 4 + r;
          float val = acc[mf][nf][r];
          if (MODE == 0) {
            float other = __shfl_xor(val, 1);  // partner d^1 lives in lane fn^1
            int d = ((g & 31) << 3) + w;
            if (d < 32) {
              int p = d >> 1;
              float ang = (float)l * __expf(-(float)p * 0.57564627324851142f);
              float cv = cosf(ang), sv = sinf(ang);
              val = (d & 1) ? (val * cv + other * sv) : (val * cv - other * sv);
            }
          }
          int n = g >> 5, d2 = ((g & 31) << 3) + w;
          op[base + ((size_t)n << 17) + d2] = f2bf(val);
        }
    }
  }
}

// -------- V transpose: vt2[head][mc][d][mloc] = vb[head][mc*32+mloc][d] -----
__global__ __launch_bounds__(256) void transpose_v_kernel(const u16* __restrict__ vb,
                                                          u16* __restrict__ vt) {
  __shared__ u16 tile[64 * 66];
  int bx = blockIdx.x;                  // head*32 + mt*4 + dt
  int head = bx >> 5, mt = (bx >> 2) & 7, dt = bx & 3;
  size_t off = (size_t)head << 17;
  int t = threadIdx.x;
#pragma unroll
  for (int it = 0; it < 2; ++it) {
    int li = it * 256 + t;
    int r = li >> 3, cs = li & 7;
    uint4 u = *(const uint4*)(vb + off + (size_t)(mt * 64 + r) * 256 + dt * 64 + cs * 8);
    *(u32*)&tile[r * 66 + cs * 8 + 0] = u.x;
    *(u32*)&tile[r * 66 + cs * 8 + 2] = u.y;
    *(u32*)&tile[r * 66 + cs * 8 + 4] = u.z;
    *(u32*)&tile[r * 66 + cs * 8 + 6] = u.w;
  }
  __syncthreads();
#pragma unroll
  for (int it = 0; it < 2; ++it) {
    int li = it * 256 + t;
    int r = li >> 3, cs = li & 7;   // r = d-local (0..63), cs = m-seg (0..7)
    u16 tmp[8];
#pragma unroll
    for (int jj = 0; jj < 8; ++jj) tmp[jj] = tile[(cs * 8 + jj) * 66 + r];
    uint4 o;
    o.x = (u32)tmp[0] | ((u32)tmp[1] << 16);
    o.y = (u32)tmp[2] | ((u32)tmp[3] << 16);
    o.z = (u32)tmp[4] | ((u32)tmp[5] << 16);
    o.w = (u32)tmp[6] | ((u32)tmp[7] << 16);
    int d = dt * 64 + r;
    // chunk-tiled: mc = mt*2 + (cs>>2); mloc = (cs&3)*8
    *(uint4*)(vt + off + (size_t)(mt * 2 + (cs >> 2)) * 8192 + (size_t)d * 32 +
              (cs & 3) * 8) = o;
  }
}

// ---------------- MFMA attention v4: staged pipeline ------------------------
// K/V staged via global_load_lds (linear LDS dest, pre-swizzled global src);
// XOR-swizzled ds_read (conflict-free); 1 barrier/chunk; prev preloaded to
// regs; qk_out stored in one burst after QK loop. LDS = exactly 64 KB.
__global__ __launch_bounds__(256, 2) void attn_kernel(
    const u16* __restrict__ q, const u16* __restrict__ k,
    const u16* __restrict__ vt, const float* __restrict__ prev,
    float* __restrict__ qk_out, u16* __restrict__ a2) {
  __shared__ uint4 sbuf4[2048];   // 32 KB staging (2 x 16 KB, double buffer)
  __shared__ uint4 pbuf4[2048];   // 32 KB S/P tile [32][512] u16, swizzled
  char* stage = (char*)sbuf4;
  char* sbb = (char*)pbuf4;

  int bx = blockIdx.x;
  int bid = (bx & 7) * 256 + (bx >> 3);   // XCD swizzle: 16 blocks/head -> 1 XCD
  int head = bid >> 4;
  int l0 = (bid & 15) << 5;
  int b = head >> 6, c = (head >> 3) & 7, nh = head & 7;
  size_t qoff = (size_t)head << 17;
  size_t poff = (size_t)head << 18;
  int tid = threadIdx.x;
  int w = tid >> 6, lane = tid & 63;
  int fn = lane & 15, fq = lane >> 4;
  int rt = w & 1, ct = w >> 1;
  int krow = ct * 16 + fn;

  // K stage addressing: per instr 1KB = 2 rows x 512B; row=lane>>5, slot=lane&31
#define STAGE_K(CUR, M0) do {                                                 \
    _Pragma("unroll") for (int _it = 0; _it < 4; ++_it) {                     \
      int _rr = (w << 3) + (_it << 1) + (lane >> 5);                          \
      const u16* _g = k + qoff + ((size_t)((M0) + _rr) << 8) +                \
                      (((lane & 31) ^ (_rr & 7)) << 3);                       \
      gl_lds16(_g, stage + (CUR) * 16384 + (((w << 3) + (_it << 1)) << 9));   \
    } } while (0)

  // V stage: chunk tile [256 d][64B]; per instr 1KB = 16 rows; row=lane>>2
#define STAGE_V(CUR, MC) do {                                                 \
    _Pragma("unroll") for (int _it = 0; _it < 4; ++_it) {                     \
      int _d = (w << 6) + (_it << 4) + (lane >> 2);                           \
      const u16* _g = vt + qoff + ((size_t)(MC) << 13) + (_d << 5) +          \
                      (((lane & 3) ^ ((_d >> 1) & 3)) << 3);                  \
      gl_lds16(_g, stage + (CUR) * 16384 + (((w << 6) + (_it << 4)) << 6));   \
    } } while (0)

  // preload Q fragments (16 rows for this wave, full K=256)
  short8 qf[8];
  const u16* qrow = q + qoff + (size_t)(l0 + rt * 16 + fn) * 256 + fq * 8;
#pragma unroll
  for (int kc = 0; kc < 8; ++kc) qf[kc] = *(const short8*)(qrow + kc * 32);

  // preload ALL prev values for this thread's S elements (64 floats)
  float pv[16][4];
  const float* prow = prev + poff + (size_t)(l0 + rt * 16 + fq * 4) * 512 + ct * 16 + fn;
#pragma unroll
  for (int mc = 0; mc < 16; ++mc)
#pragma unroll
    for (int r = 0; r < 4; ++r) pv[mc][r] = prow[r * 512 + mc * 32];

  STAGE_K(0, 0);
  __syncthreads();

  // ---- S = QK^T/16 + prev : staged, 1 barrier/chunk ----
#pragma unroll
  for (int mc = 0; mc < 16; ++mc) {
    if (mc < 15) STAGE_K((mc + 1) & 1, (mc + 1) * 32);
    floatx4 acc = {0.f, 0.f, 0.f, 0.f};
#pragma unroll
    for (int kc = 0; kc < 8; ++kc) {
      short8 bfr = *(const short8*)(stage + ((mc & 1) << 14) + (krow << 9) +
                                    ((((kc << 2) + fq) ^ (fn & 7)) << 4));
      acc = __builtin_amdgcn_mfma_f32_16x16x32_bf16(qf[kc], bfr, acc, 0, 0, 0);
    }
#pragma unroll
    for (int r = 0; r < 4; ++r) {
      float sv = acc[r] * 0.0625f + pv[mc][r];
      pv[mc][r] = sv;  // keep for deferred qk_out store
      int row = rt * 16 + fq * 4 + r;
      *(u16*)(sbb + (row << 10) +
              ((((mc << 2) + (ct << 1) + (fn >> 3)) ^ (row & 7)) << 4) +
              ((fn & 7) << 1)) = f2bf(sv);
    }
    __syncthreads();
  }

  // deferred qk_out burst (acks drain under softmax)
  float* qrow_out = qk_out + poff + (size_t)(l0 + rt * 16 + fq * 4) * 512 + ct * 16 + fn;
#pragma unroll
  for (int mc = 0; mc < 16; ++mc)
#pragma unroll
    for (int r = 0; r < 4; ++r) qrow_out[r * 512 + mc * 32] = pv[mc][r];

  // ---- softmax over rows (8 threads/row, swizzled slots) ----
  {
    int srow = tid >> 3, sseg = tid & 7;
    int ss = sseg ^ (srow & 7);
    char* sp = sbb + (srow << 10);
    float mx = -1e30f;
#pragma unroll
    for (int ii = 0; ii < 8; ++ii) {
      uint4 u = *(const uint4*)(sp + (((ii << 3) + ss) << 4));
      mx = fmaxf(mx, fmaxf(fmaxf(fmaxf(bf2f(u.x & 0xffff), bf2f(u.x >> 16)),
                                 fmaxf(bf2f(u.y & 0xffff), bf2f(u.y >> 16))),
                           fmaxf(fmaxf(bf2f(u.z & 0xffff), bf2f(u.z >> 16)),
                                 fmaxf(bf2f(u.w & 0xffff), bf2f(u.w >> 16)))));
    }
#pragma unroll
    for (int o = 1; o < 8; o <<= 1) mx = fmaxf(mx, __shfl_xor(mx, o));
    float sum = 0.f;
#pragma unroll
    for (int ii = 0; ii < 8; ++ii) {
      uint4 u = *(const uint4*)(sp + (((ii << 3) + ss) << 4));
      float e0 = __expf(bf2f(u.x & 0xffff) - mx), e1 = __expf(bf2f(u.x >> 16) - mx);
      float e2 = __expf(bf2f(u.y & 0xffff) - mx), e3 = __expf(bf2f(u.y >> 16) - mx);
      float e4 = __expf(bf2f(u.z & 0xffff) - mx), e5 = __expf(bf2f(u.z >> 16) - mx);
      float e6 = __expf(bf2f(u.w & 0xffff) - mx), e7 = __expf(bf2f(u.w >> 16) - mx);
      sum += e0 + e1 + e2 + e3 + e4 + e5 + e6 + e7;
      uint4 o;
      o.x = (u32)f2bf(e0) | ((u32)f2bf(e1) << 16);
      o.y = (u32)f2bf(e2) | ((u32)f2bf(e3) << 16);
      o.z = (u32)f2bf(e4) | ((u32)f2bf(e5) << 16);
      o.w = (u32)f2bf(e6) | ((u32)f2bf(e7) << 16);
      *(uint4*)(sp + (((ii << 3) + ss) << 4)) = o;
    }
#pragma unroll
    for (int o = 1; o < 8; o <<= 1) sum += __shfl_xor(sum, o);
    if (sseg == 0) ((float*)(stage + 16384))[srow] = 1.0f / sum;
  }
  __syncthreads();

  // ---- O = P V : staged, 1 barrier/chunk ----
  // read rinv (parked in buf1) BEFORE PV staging can overwrite it
  float riv[4];
#pragma unroll
  for (int r = 0; r < 4; ++r)
    riv[r] = ((const float*)(stage + 16384))[rt * 16 + fq * 4 + r];
  STAGE_V(0, 0);
  __syncthreads();

  floatx4 oacc[8];
#pragma unroll
  for (int dt = 0; dt < 8; ++dt) oacc[dt] = (floatx4){0.f, 0.f, 0.f, 0.f};

  int prowp = rt * 16 + fn;  // P fragment row
  int vswz = (fn >> 1) & 3;
#pragma unroll
  for (int mc = 0; mc < 16; ++mc) {
    if (mc < 15) STAGE_V((mc + 1) & 1, mc + 1);
    short8 af = *(const short8*)(sbb + (prowp << 10) +
                                 ((((mc << 2) + fq) ^ (fn & 7)) << 4));
#pragma unroll
    for (int dt = 0; dt < 8; ++dt) {
      int d = ct * 128 + dt * 16 + fn;
      short8 bv = *(const short8*)(stage + ((mc & 1) << 14) + (d << 6) +
                                   ((fq ^ vswz) << 4));
      oacc[dt] = __builtin_amdgcn_mfma_f32_16x16x32_bf16(af, bv, oacc[dt], 0, 0, 0);
    }
    if (mc < 15) __syncthreads();
  }

#pragma unroll
  for (int dt = 0; dt < 8; ++dt) {
#pragma unroll
    for (int r = 0; r < 4; ++r) {
      int lrow = l0 + rt * 16 + fq * 4 + r;
      int d = ct * 128 + dt * 16 + fn;
      int bl = b * 512 + lrow;
      // w-major a2: feature f = nh*256+d -> [ (f&7)*256 + (f>>3) ]
      a2[(size_t)(bl * 8 + c) * 2048 + ((d & 7) << 8) + (nh << 5) + (d >> 3)] =
          f2bf(oacc[dt][r] * riv[r]);
    }
  }
#undef STAGE_K
#undef STAGE_V
}

extern "C" void kernel_launch(void* const* d_in, const int* in_sizes, int n_in,
                              void* d_out, int out_size, void* d_ws, size_t ws_size,
                              hipStream_t stream) {
  const float* x    = (const float*)d_in[0];
  const float* prev = (const float*)d_in[1];
  const float* cqw  = (const float*)d_in[2];
  const float* ckw  = (const float*)d_in[3];
  const float* cvw  = (const float*)d_in[4];
  const float* wq   = (const float*)d_in[5];
  const float* wk   = (const float*)d_in[6];
  const float* wv   = (const float*)d_in[7];
  const float* wo   = (const float*)d_in[8];

  float* out    = (float*)d_out;
  float* qk_out = out + 16777216;

  char* wsb = (char*)d_ws;
  u16* wbf    = (u16*)wsb;                         // 4 MB (in old 8 MB slot)
  u16* convq  = (u16*)(wsb + 8388608);             // each 33.5 MB
  u16* convk  = convq + 16777216;
  u16* convv  = convk + 16777216;
  u16* qb     = convv + 16777216;
  u16* kb     = qb + 16777216;
  u16* vb     = kb + 16777216;
  u16* vtb    = vb + 16777216;
  u16* a2     = vtb + 16777216;
  // total ~277 MB

  convert_w_kernel<<<dim3(2048, 4), 256, 0, stream>>>(wq, wk, wv, wo, wbf);
  conv_fused_kernel<<<2048, 256, 0, stream>>>(x, cqw, ckw, cvw, convq, convk, convv);
  mlin_mfma_kernel<0><<<1024, 256, 0, stream>>>(convq, wbf, qb);
  mlin_mfma_kernel<0><<<1024, 256, 0, stream>>>(convk, wbf + 524288, kb);
  mlin_mfma_kernel<1><<<1024, 256, 0, stream>>>(convv, wbf + 1048576, vb);
  transpose_v_kernel<<<4096, 256, 0, stream>>>(vb, vtb);
  attn_kernel<<<2048, 256, 0, stream>>>(qb, kb, vtb, prev, qk_out, a2);
  mlin_mfma_kernel<2><<<1024, 256, 0, stream>>>(a2, wbf + 1572864, out);
}